// Round 10
// baseline (165.099 us; speedup 1.0000x reference)
//
#include <hip/hip_runtime.h>

#define S_LEN 2048
#define BATCH 2
#define HDIM 1024
#define NH 16
#define DH 64
#define WINSZ 512
#define MROWS (BATCH * S_LEN)

typedef __attribute__((ext_vector_type(8))) short bfrag;
typedef __attribute__((ext_vector_type(4))) float f32x4;
typedef __attribute__((ext_vector_type(4))) int i128;

__device__ __forceinline__ short f2bf(float f) {
    union { float f; unsigned u; } v;
    v.f = f;
    unsigned r = v.u + 0x7fffu + ((v.u >> 16) & 1u);
    return (short)(r >> 16);
}

__device__ __forceinline__ void gload_lds16(const short* g, short* l) {
    __builtin_amdgcn_global_load_lds(
        (const __attribute__((address_space(1))) unsigned int*)g,
        (__attribute__((address_space(3))) unsigned int*)l, 16, 0, 0);
}

// ---------------- fused prep: x cast (blocks 0..4095), Wqkv^T (4096..7167), Wout^T (7168..8191) ----
__global__ __launch_bounds__(256)
void prep_kernel(const float* __restrict__ x, const float* __restrict__ Wqkv,
                 const float* __restrict__ Wout,
                 short* __restrict__ x_bf, short* __restrict__ wqkv_t, short* __restrict__ wout_t)
{
    __shared__ float tile[32][33];
    const int bid = blockIdx.x;
    const int t = threadIdx.x;

    if (bid < 4096) {
        int i = bid * 256 + t;
        float4 v = ((const float4*)x)[i];
        union { short s[4]; int2 p; } u;
        u.s[0] = f2bf(v.x); u.s[1] = f2bf(v.y); u.s[2] = f2bf(v.z); u.s[3] = f2bf(v.w);
        ((int2*)x_bf)[i] = u.p;
        return;
    }

    const float* in;
    short* out;
    int R, C, bx, by;
    if (bid < 7168) {
        int lb = bid - 4096;
        in = Wqkv; out = wqkv_t; R = 1024; C = 3072;
        bx = lb % 96; by = lb / 96;
    } else {
        int lb = bid - 7168;
        in = Wout; out = wout_t; R = 1024; C = 1024;
        bx = lb & 31; by = lb >> 5;
    }
    int tc0 = bx * 32, tr0 = by * 32;
    int c = t & 31, r0 = t >> 5;
    #pragma unroll
    for (int k = 0; k < 4; ++k) {
        int r = r0 + k * 8;
        tile[r][c] = in[(size_t)(tr0 + r) * C + tc0 + c];
    }
    __syncthreads();
    int r2p = (t & 15) << 1, c0 = t >> 4;
    #pragma unroll
    for (int k = 0; k < 2; ++k) {
        int c2 = c0 + k * 16;
        union { short sh[2]; int w; } u;
        u.sh[0] = f2bf(tile[r2p][c2]);
        u.sh[1] = f2bf(tile[r2p + 1][c2]);
        *(int*)(&out[(size_t)(tc0 + c2) * R + tr0 + r2p]) = u.w;
    }
}

// ---------------- QKV GEMM: x_bf (M x 1024) @ wqkv_t (3072 x 1024) ----------------
// counted-vmcnt two-barrier pipeline (T4); BK=32 keeps LDS 32KB -> 3 blocks/CU
__global__ __launch_bounds__(256, 3)
void gemm_qkv(const short* __restrict__ A, const short* __restrict__ Bt,
              short* __restrict__ qk_rm, short* __restrict__ vto)
{
    __shared__ __align__(16) short smraw[17408];
    short (*Al)[4096] = (short(*)[4096])smraw;
    short (*Bl)[4096] = (short(*)[4096])(smraw + 8192);
    const int K = HDIM;
    const int t = threadIdx.x;
    const int lane = t & 63;
    const int wave = t >> 6;
    const int wr = wave >> 1, wc = wave & 1;
    const int m0 = blockIdx.y * 128, n0 = blockIdx.x * 128;
    const int lq = lane & 15;
    const int g = lane >> 4;
    const int lk8 = g << 3;

    f32x4 acc[4][4];
    #pragma unroll
    for (int m = 0; m < 4; ++m)
        #pragma unroll
        for (int n = 0; n < 4; ++n)
            acc[m][n] = (f32x4){0.f, 0.f, 0.f, 0.f};

    const int row0s = t >> 2, col0s = (t & 3) << 3;
    const int row1s = (256 + t) >> 2;
    const size_t dst0 = (size_t)(wave * 64) * 8;
    const size_t dst1 = (size_t)(256 + wave * 64) * 8;

    auto stage = [&](int k0, int sb) {
        gload_lds16(&A[(size_t)(m0 + row0s) * K + k0 + col0s], &Al[sb][0] + dst0);
        gload_lds16(&Bt[(size_t)(n0 + row0s) * K + k0 + col0s], &Bl[sb][0] + dst0);
        gload_lds16(&A[(size_t)(m0 + row1s) * K + k0 + col0s], &Al[sb][0] + dst1);
        gload_lds16(&Bt[(size_t)(n0 + row1s) * K + k0 + col0s], &Bl[sb][0] + dst1);
    };

    const int nk = K >> 5;   // 32
    stage(0, 0);             // 4 vmem outstanding
    for (int ki = 0; ki < nk; ++ki) {
        const int cur = ki & 1;
        if (ki + 1 < nk) {
            stage((ki + 1) << 5, cur ^ 1);                       // +4 -> 8 outstanding
            asm volatile("s_waitcnt vmcnt(4)" ::: "memory");     // tile ki's 4 landed
        } else {
            asm volatile("s_waitcnt vmcnt(0)" ::: "memory");
        }
        __builtin_amdgcn_sched_barrier(0);
        __builtin_amdgcn_s_barrier();          // #1: all waves' tile-ki DMA visible
        __builtin_amdgcn_sched_barrier(0);
        bfrag af[4], bfr[4];
        #pragma unroll
        for (int m = 0; m < 4; ++m)
            af[m] = *(const bfrag*)(&Al[cur][(wr * 64 + m * 16 + lq) * 32 + lk8]);
        #pragma unroll
        for (int n = 0; n < 4; ++n)
            bfr[n] = *(const bfrag*)(&Bl[cur][(wc * 64 + n * 16 + lq) * 32 + lk8]);
        #pragma unroll
        for (int m = 0; m < 4; ++m)
            #pragma unroll
            for (int n = 0; n < 4; ++n)
                acc[m][n] = __builtin_amdgcn_mfma_f32_16x16x32_bf16(af[m], bfr[n], acc[m][n], 0, 0, 0);
        asm volatile("s_waitcnt lgkmcnt(0)" ::: "memory");       // my buf[cur] reads serviced
        __builtin_amdgcn_sched_barrier(0);
        __builtin_amdgcn_s_barrier();          // #2: buf[cur] reusable next iter
        __builtin_amdgcn_sched_barrier(0);
    }

    if (n0 < 2048) {
        #pragma unroll
        for (int m = 0; m < 4; ++m)
            #pragma unroll
            for (int n = 0; n < 4; ++n) {
                int col = n0 + wc * 64 + n * 16 + lq;
                int row0 = m0 + wr * 64 + m * 16 + g * 4;
                #pragma unroll
                for (int r = 0; r < 4; ++r)
                    qk_rm[(size_t)(row0 + r) * 2048 + col] = f2bf(acc[m][n][r]);
            }
    } else {
        short* T = smraw;   // [128][136]
        #pragma unroll
        for (int m = 0; m < 4; ++m)
            #pragma unroll
            for (int n = 0; n < 4; ++n) {
                int cl = wc * 64 + n * 16 + lq;
                int rl0 = wr * 64 + m * 16 + g * 4;
                union { short sh[4]; int2 w; } u;
                #pragma unroll
                for (int r = 0; r < 4; ++r) u.sh[r] = f2bf(acc[m][n][r]);
                *(int2*)(&T[cl * 136 + rl0]) = u.w;
            }
        __syncthreads();
        const int b = m0 >> 11, sbase = m0 & 2047;
        const int h0 = (n0 - 2048) >> 6;
        #pragma unroll
        for (int i = 0; i < 8; ++i) {
            int c2 = i * 256 + t;
            int rv = c2 >> 4;
            int sc = (c2 & 15) << 3;
            int h = h0 + (rv >> 6), dh = rv & 63;
            i128 v = *(const i128*)(&T[rv * 136 + sc]);
            *(i128*)(&vto[((size_t)((b * NH + h) * DH + dh)) * S_LEN + sbase + sc]) = v;
        }
    }
}

// ---------------- out GEMM: attno (M x 1024) @ wout_t (1024 x 1024) -> fp32, BK=64 ----------------
__global__ __launch_bounds__(256, 2)
void gemm_out(const short* __restrict__ A, const short* __restrict__ Bt,
              float* __restrict__ co)
{
    __shared__ __align__(16) short Al[2][128 * 64];
    __shared__ __align__(16) short Bl[2][128 * 64];
    const int K = HDIM, N = HDIM;
    const int t = threadIdx.x;
    const int lane = t & 63;
    const int wave = t >> 6;
    const int wr = wave >> 1, wc = wave & 1;
    const int m0 = blockIdx.y * 128, n0 = blockIdx.x * 128;
    const int lq = lane & 15;
    const int g = lane >> 4;

    f32x4 acc[4][4];
    #pragma unroll
    for (int m = 0; m < 4; ++m)
        #pragma unroll
        for (int n = 0; n < 4; ++n)
            acc[m][n] = (f32x4){0.f, 0.f, 0.f, 0.f};

    auto stage = [&](int k0, int sb) {
        #pragma unroll
        for (int q = 0; q < 4; ++q) {
            int chunk = q * 256 + t;
            int row = chunk >> 3, col = (chunk & 7) << 3;
            size_t dst = (size_t)(q * 256 + wave * 64) * 8;
            gload_lds16(&A[(size_t)(m0 + row) * K + k0 + col], &Al[sb][0] + dst);
            gload_lds16(&Bt[(size_t)(n0 + row) * K + k0 + col], &Bl[sb][0] + dst);
        }
    };

    const int nk = K >> 6;   // 16
    stage(0, 0);             // 8 vmem outstanding
    for (int ki = 0; ki < nk; ++ki) {
        const int cur = ki & 1;
        if (ki + 1 < nk) {
            stage((ki + 1) << 6, cur ^ 1);
            asm volatile("s_waitcnt vmcnt(8)" ::: "memory");
        } else {
            asm volatile("s_waitcnt vmcnt(0)" ::: "memory");
        }
        __builtin_amdgcn_sched_barrier(0);
        __builtin_amdgcn_s_barrier();
        __builtin_amdgcn_sched_barrier(0);
        bfrag af[4][2], bfr[4][2];
        #pragma unroll
        for (int m = 0; m < 4; ++m)
            #pragma unroll
            for (int ks = 0; ks < 2; ++ks)
                af[m][ks] = *(const bfrag*)(&Al[cur][(wr * 64 + m * 16 + lq) * 64 + ks * 32 + (g << 3)]);
        #pragma unroll
        for (int n = 0; n < 4; ++n)
            #pragma unroll
            for (int ks = 0; ks < 2; ++ks)
                bfr[n][ks] = *(const bfrag*)(&Bl[cur][(wc * 64 + n * 16 + lq) * 64 + ks * 32 + (g << 3)]);
        #pragma unroll
        for (int m = 0; m < 4; ++m)
            #pragma unroll
            for (int n = 0; n < 4; ++n) {
                acc[m][n] = __builtin_amdgcn_mfma_f32_16x16x32_bf16(af[m][0], bfr[n][0], acc[m][n], 0, 0, 0);
                acc[m][n] = __builtin_amdgcn_mfma_f32_16x16x32_bf16(af[m][1], bfr[n][1], acc[m][n], 0, 0, 0);
            }
        asm volatile("s_waitcnt lgkmcnt(0)" ::: "memory");
        __builtin_amdgcn_sched_barrier(0);
        __builtin_amdgcn_s_barrier();
        __builtin_amdgcn_sched_barrier(0);
    }

    #pragma unroll
    for (int m = 0; m < 4; ++m)
        #pragma unroll
        for (int n = 0; n < 4; ++n) {
            int col = n0 + wc * 64 + n * 16 + lq;
            int row0 = m0 + wr * 64 + m * 16 + g * 4;
            #pragma unroll
            for (int r = 0; r < 4; ++r)
                co[(size_t)(row0 + r) * N + col] = acc[m][n][r];
        }
}

// ---------------- sliding-window flash attention: 64-q blocks, deferred-PV, counted vmcnt, defer-max ----------------
__global__ __launch_bounds__(256, 4)
void attn_kernel(const short* __restrict__ qk, const short* __restrict__ vt,
                 short* __restrict__ attno)
{
    __shared__ __align__(16) short Kl[2][64 * 64];
    __shared__ __align__(16) short Vl[2][64 * 64];
    __shared__ __align__(16) short Pl[4][16 * 64];

    const int bid = blockIdx.x;
    const int logical = (bid & 7) * 128 + (bid >> 3);   // XCD-grouping (1024 % 8 == 0, bijective)
    const int qblk = logical & 31;
    const int bh = logical >> 5;
    const int b = bh >> 4, h = bh & 15;

    const int t = threadIdx.x;
    const int wave = t >> 6, lane = t & 63;
    const int qb0 = qblk * 64;
    const int i0 = qb0 + wave * 16;
    const short* qbase = qk + (size_t)b * S_LEN * 2048 + h * 64;
    const short* kbase = qk + (size_t)b * S_LEN * 2048 + 1024 + h * 64;
    const short* vp = vt + (size_t)bh * DH * S_LEN;
    char* myP = (char*)&Pl[wave][0];

    const int lq = lane & 15;
    const int g = lane >> 4;
    const int swz = (lq & 7) << 4;
    const int l7 = lq & 7;
    const int qi = i0 + lq;

    bfrag qf[2];
    qf[0] = *(const bfrag*)(&qbase[(size_t)(i0 + lq) * 2048 + (g << 3)]);
    qf[1] = *(const bfrag*)(&qbase[(size_t)(i0 + lq) * 2048 + 32 + (g << 3)]);

    f32x4 oacc[4];
    #pragma unroll
    for (int d = 0; d < 4; ++d) oacc[d] = (f32x4){0.f, 0.f, 0.f, 0.f};
    float m2 = -1e30f, lrun = 0.f, scale_prev = 1.f;
    bool defer_prev = true;            // scale_prev==1 -> skip rescale
    const float QSCALE = 0.125f * 1.44269504f;

    bfrag pf_prev[2];
    bfrag vf_prev[2][4];

    int j_lo = qb0 - (WINSZ - 1);
    if (j_lo < 0) j_lo = 0;
    j_lo &= ~63;
    const int nT = ((qb0 + 64) - j_lo) >> 6;

    auto stage = [&](int jrel, short* kbuf, short* vbuf) {
        #pragma unroll
        for (int qq = 0; qq < 2; ++qq) {
            int chunk = qq * 256 + wave * 64 + lane;
            int row = chunk >> 3;
            int cc = (chunk & 7) ^ (row & 7);
            short* kdst = kbuf + (size_t)(qq * 256 + wave * 64) * 8;
            short* vdst = vbuf + (size_t)(qq * 256 + wave * 64) * 8;
            gload_lds16(kbase + (size_t)(j_lo + jrel + row) * 2048 + cc * 8, kdst);
            gload_lds16(vp + (size_t)row * S_LEN + j_lo + jrel + cc * 8, vdst);
        }
    };

    stage(0, Kl[0], Vl[0]);   // 4 vmem outstanding

    for (int ti = 0; ti < nT; ++ti) {
        const int cur = ti & 1;
        const int j0 = j_lo + ti * 64;
        const bool more = (ti + 1 < nT);
        if (more) stage((ti + 1) * 64, Kl[cur ^ 1], Vl[cur ^ 1]);   // +4 -> 8 outstanding

        // ---- deferred PV(ti-1): pure-register MFMA fills the load wait ----
        if (ti > 0) {
            if (!defer_prev) {
                #pragma unroll
                for (int d = 0; d < 4; ++d) {
                    f32x4 o = oacc[d];
                    o[0] *= scale_prev; o[1] *= scale_prev; o[2] *= scale_prev; o[3] *= scale_prev;
                    oacc[d] = o;
                }
            }
            __builtin_amdgcn_s_setprio(1);
            #pragma unroll
            for (int kt = 0; kt < 2; ++kt)
                #pragma unroll
                for (int d = 0; d < 4; ++d)
                    oacc[d] = __builtin_amdgcn_mfma_f32_16x16x32_bf16(vf_prev[kt][d], pf_prev[kt], oacc[d], 0, 0, 0);
            __builtin_amdgcn_s_setprio(0);
        }

        if (more) asm volatile("s_waitcnt vmcnt(4)" ::: "memory");
        else      asm volatile("s_waitcnt vmcnt(0)" ::: "memory");
        __builtin_amdgcn_sched_barrier(0);
        __builtin_amdgcn_s_barrier();        // #1: all waves' tile-ti DMA visible
        __builtin_amdgcn_sched_barrier(0);

        const short* Kc = Kl[cur];
        const short* Vc = Vl[cur];

        // ---- QK^T swapped ----
        f32x4 sc[4];
        __builtin_amdgcn_s_setprio(1);
        #pragma unroll
        for (int tc = 0; tc < 4; ++tc) {
            bfrag a0 = *(const bfrag*)(&Kc[(tc * 16 + lq) * 64 + ((g ^ l7) << 3)]);
            bfrag a1 = *(const bfrag*)(&Kc[(tc * 16 + lq) * 64 + (((4 | g) ^ l7) << 3)]);
            f32x4 z = (f32x4){0.f, 0.f, 0.f, 0.f};
            z = __builtin_amdgcn_mfma_f32_16x16x32_bf16(a0, qf[0], z, 0, 0, 0);
            z = __builtin_amdgcn_mfma_f32_16x16x32_bf16(a1, qf[1], z, 0, 0, 0);
            sc[tc] = z;
        }
        __builtin_amdgcn_s_setprio(0);

        // ---- softmax (per-lane + 2 shuffles) with defer-max (T13, THR=8) ----
        const bool nomask = (j0 >= i0 - (WINSZ - 16)) && (j0 + 63 <= i0);
        float s[4][4];
        float pm = -1e30f;
        #pragma unroll
        for (int tc = 0; tc < 4; ++tc)
            #pragma unroll
            for (int r = 0; r < 4; ++r) {
                float sv = sc[tc][r] * QSCALE;
                if (!nomask) {
                    int kj = j0 + tc * 16 + 4 * g + r;
                    sv = ((kj <= qi) && (kj > qi - WINSZ)) ? sv : -1e30f;
                }
                s[tc][r] = sv;
                pm = fmaxf(pm, sv);
            }
        pm = fmaxf(pm, __shfl_xor(pm, 16));
        pm = fmaxf(pm, __shfl_xor(pm, 32));
        bool defer_i = __all(pm <= m2 + 8.f);
        float scale_i = 1.f;
        if (!defer_i) {
            float mnew = fmaxf(m2, pm);
            scale_i = exp2f(m2 - mnew);
            m2 = mnew;
        }
        float p[4][4];
        float rs = 0.f;
        #pragma unroll
        for (int tc = 0; tc < 4; ++tc)
            #pragma unroll
            for (int r = 0; r < 4; ++r) {
                p[tc][r] = exp2f(s[tc][r] - m2);
                rs += p[tc][r];
            }
        rs += __shfl_xor(rs, 16);
        rs += __shfl_xor(rs, 32);
        lrun = lrun * scale_i + rs;
        scale_prev = scale_i;
        defer_prev = defer_i;

        // ---- P(ti) -> LDS, then P/V reads for NEXT iter ----
        #pragma unroll
        for (int tc = 0; tc < 4; ++tc) {
            union { short sh[4]; int2 w; } u;
            u.sh[0] = f2bf(p[tc][0]); u.sh[1] = f2bf(p[tc][1]);
            u.sh[2] = f2bf(p[tc][2]); u.sh[3] = f2bf(p[tc][3]);
            int wb = (lq * 128 + tc * 32 + g * 8) ^ swz;
            *(int2*)(myP + wb) = u.w;
        }
        #pragma unroll
        for (int kt = 0; kt < 2; ++kt) {
            int rb = (lq * 128 + kt * 64 + g * 16) ^ swz;
            pf_prev[kt] = *(const bfrag*)(myP + rb);
            #pragma unroll
            for (int d = 0; d < 4; ++d)
                vf_prev[kt][d] = *(const bfrag*)(&Vc[(d * 16 + lq) * 64 + (((kt * 4 + g) ^ l7) << 3)]);
        }
        asm volatile("s_waitcnt lgkmcnt(0)" ::: "memory");
        __builtin_amdgcn_sched_barrier(0);
        __builtin_amdgcn_s_barrier();        // #2: buf[cur] reusable next iter
        __builtin_amdgcn_sched_barrier(0);
    }

    // ---- flush PV(nT-1) ----
    if (!defer_prev) {
        #pragma unroll
        for (int d = 0; d < 4; ++d) {
            f32x4 o = oacc[d];
            o[0] *= scale_prev; o[1] *= scale_prev; o[2] *= scale_prev; o[3] *= scale_prev;
            oacc[d] = o;
        }
    }
    #pragma unroll
    for (int kt = 0; kt < 2; ++kt)
        #pragma unroll
        for (int d = 0; d < 4; ++d)
            oacc[d] = __builtin_amdgcn_mfma_f32_16x16x32_bf16(vf_prev[kt][d], pf_prev[kt], oacc[d], 0, 0, 0);

    const float inv_l = 1.f / lrun;
    size_t rowbase = ((size_t)(b * S_LEN + qi)) * HDIM + h * DH;
    #pragma unroll
    for (int d = 0; d < 4; ++d) {
        union { short sh[4]; int2 w; } u;
        #pragma unroll
        for (int r = 0; r < 4; ++r)
            u.sh[r] = f2bf(oacc[d][r] * inv_l);
        *(int2*)(&attno[rowbase + d * 16 + 4 * g]) = u.w;
    }
}

extern "C" void kernel_launch(void* const* d_in, const int* in_sizes, int n_in,
                              void* d_out, int out_size, void* d_ws, size_t ws_size,
                              hipStream_t stream) {
    const float* x = (const float*)d_in[0];
    const float* Wqkv = (const float*)d_in[1];
    const float* Wout = (const float*)d_in[2];
    float* out = (float*)d_out;
    char* ws = (char*)d_ws;

    short* x_bf   = (short*)(ws);                    // 4096x1024 bf16 (8 MB); reused as attno
    short* wqkv_t = (short*)(ws + 8388608);          // 3072x1024      (6 MB)
    short* wout_t = (short*)(ws + 14680064);         // 1024x1024      (2 MB)
    short* qk_rm  = (short*)(ws + 16777216);         // 4096x2048 bf16 (16 MB)
    short* v_t    = (short*)(ws + 33554432);         // [b][h][dh][s]  (8 MB)
    short* attno  = x_bf;                            // alias: x_bf dead after QKV GEMM

    prep_kernel<<<8192, 256, 0, stream>>>(x, Wqkv, Wout, x_bf, wqkv_t, wout_t);
    gemm_qkv<<<dim3(24, 32), 256, 0, stream>>>(x_bf, wqkv_t, qk_rm, v_t);
    attn_kernel<<<dim3(BATCH * NH * (S_LEN / 64)), 256, 0, stream>>>(qk_rm, v_t, attno);
    gemm_out<<<dim3(8, 32), 256, 0, stream>>>(attno, wout_t, out);
}

// Round 11
// 162.482 us; speedup vs baseline: 1.0161x; 1.0161x over previous
//
#include <hip/hip_runtime.h>

#define S_LEN 2048
#define BATCH 2
#define HDIM 1024
#define NH 16
#define DH 64
#define WINSZ 512
#define MROWS (BATCH * S_LEN)

typedef __attribute__((ext_vector_type(8))) short bfrag;
typedef __attribute__((ext_vector_type(4))) float f32x4;
typedef __attribute__((ext_vector_type(4))) int i128;

__device__ __forceinline__ short f2bf(float f) {
    union { float f; unsigned u; } v;
    v.f = f;
    unsigned r = v.u + 0x7fffu + ((v.u >> 16) & 1u);
    return (short)(r >> 16);
}

__device__ __forceinline__ void gload_lds16(const short* g, short* l) {
    __builtin_amdgcn_global_load_lds(
        (const __attribute__((address_space(1))) unsigned int*)g,
        (__attribute__((address_space(3))) unsigned int*)l, 16, 0, 0);
}

// ---------------- fused prep: x cast (blocks 0..4095), Wqkv^T (4096..7167), Wout^T (7168..8191) ----
__global__ __launch_bounds__(256)
void prep_kernel(const float* __restrict__ x, const float* __restrict__ Wqkv,
                 const float* __restrict__ Wout,
                 short* __restrict__ x_bf, short* __restrict__ wqkv_t, short* __restrict__ wout_t)
{
    __shared__ float tile[32][33];
    const int bid = blockIdx.x;
    const int t = threadIdx.x;

    if (bid < 4096) {
        int i = bid * 256 + t;
        float4 v = ((const float4*)x)[i];
        union { short s[4]; int2 p; } u;
        u.s[0] = f2bf(v.x); u.s[1] = f2bf(v.y); u.s[2] = f2bf(v.z); u.s[3] = f2bf(v.w);
        ((int2*)x_bf)[i] = u.p;
        return;
    }

    const float* in;
    short* out;
    int R, C, bx, by;
    if (bid < 7168) {
        int lb = bid - 4096;
        in = Wqkv; out = wqkv_t; R = 1024; C = 3072;
        bx = lb % 96; by = lb / 96;
    } else {
        int lb = bid - 7168;
        in = Wout; out = wout_t; R = 1024; C = 1024;
        bx = lb & 31; by = lb >> 5;
    }
    int tc0 = bx * 32, tr0 = by * 32;
    int c = t & 31, r0 = t >> 5;
    #pragma unroll
    for (int k = 0; k < 4; ++k) {
        int r = r0 + k * 8;
        tile[r][c] = in[(size_t)(tr0 + r) * C + tc0 + c];
    }
    __syncthreads();
    int r2p = (t & 15) << 1, c0 = t >> 4;
    #pragma unroll
    for (int k = 0; k < 2; ++k) {
        int c2 = c0 + k * 16;
        union { short sh[2]; int w; } u;
        u.sh[0] = f2bf(tile[r2p][c2]);
        u.sh[1] = f2bf(tile[r2p + 1][c2]);
        *(int*)(&out[(size_t)(tc0 + c2) * R + tr0 + r2p]) = u.w;
    }
}

// ---------------- QKV GEMM: x_bf (M x 1024) @ wqkv_t (3072 x 1024) ----------------
// counted-vmcnt two-barrier pipeline (T4) + T2 chunk-XOR LDS swizzle (2-way banks)
__global__ __launch_bounds__(256, 3)
void gemm_qkv(const short* __restrict__ A, const short* __restrict__ Bt,
              short* __restrict__ qk_rm, short* __restrict__ vto)
{
    __shared__ __align__(16) short smraw[17408];
    short (*Al)[4096] = (short(*)[4096])smraw;
    short (*Bl)[4096] = (short(*)[4096])(smraw + 8192);
    const int K = HDIM;
    const int t = threadIdx.x;
    const int lane = t & 63;
    const int wave = t >> 6;
    const int wr = wave >> 1, wc = wave & 1;
    const int m0 = blockIdx.y * 128, n0 = blockIdx.x * 128;
    const int lq = lane & 15;
    const int g = lane >> 4;

    f32x4 acc[4][4];
    #pragma unroll
    for (int m = 0; m < 4; ++m)
        #pragma unroll
        for (int n = 0; n < 4; ++n)
            acc[m][n] = (f32x4){0.f, 0.f, 0.f, 0.f};

    // staging: chunk ci -> row=ci>>2, LDS position (ci&3); GLOBAL col pre-swizzled so that
    // position p of row r holds logical chunk p ^ (r&3) ^ ((r>>2)&3)   [rule #21 both-sides]
    const int row0s = t >> 2;
    const int row1s = (256 + t) >> 2;
    const int scol = ((t >> 2) & 3) ^ ((t >> 4) & 3);       // same for row0s and row1s
    const int col0s = (((t & 3) ^ scol)) << 3;
    const size_t dst0 = (size_t)(wave * 64) * 8;
    const size_t dst1 = (size_t)(256 + wave * 64) * 8;

    // fragment read: logical k-chunk g of row (..+lq) sits at position g ^ (lq&3) ^ ((lq>>2)&3)
    const int lkA = ((g ^ (lq & 3) ^ ((lq >> 2) & 3)) << 3);

    auto stage = [&](int k0, int sb) {
        gload_lds16(&A[(size_t)(m0 + row0s) * K + k0 + col0s], &Al[sb][0] + dst0);
        gload_lds16(&Bt[(size_t)(n0 + row0s) * K + k0 + col0s], &Bl[sb][0] + dst0);
        gload_lds16(&A[(size_t)(m0 + row1s) * K + k0 + col0s], &Al[sb][0] + dst1);
        gload_lds16(&Bt[(size_t)(n0 + row1s) * K + k0 + col0s], &Bl[sb][0] + dst1);
    };

    const int nk = K >> 5;   // 32
    stage(0, 0);             // 4 vmem outstanding
    for (int ki = 0; ki < nk; ++ki) {
        const int cur = ki & 1;
        if (ki + 1 < nk) {
            stage((ki + 1) << 5, cur ^ 1);                       // +4 -> 8 outstanding
            asm volatile("s_waitcnt vmcnt(4)" ::: "memory");     // tile ki's 4 landed
        } else {
            asm volatile("s_waitcnt vmcnt(0)" ::: "memory");
        }
        __builtin_amdgcn_sched_barrier(0);
        __builtin_amdgcn_s_barrier();          // #1: all waves' tile-ki DMA visible
        __builtin_amdgcn_sched_barrier(0);
        bfrag af[4], bfr[4];
        #pragma unroll
        for (int m = 0; m < 4; ++m)
            af[m] = *(const bfrag*)(&Al[cur][(wr * 64 + m * 16 + lq) * 32 + lkA]);
        #pragma unroll
        for (int n = 0; n < 4; ++n)
            bfr[n] = *(const bfrag*)(&Bl[cur][(wc * 64 + n * 16 + lq) * 32 + lkA]);
        #pragma unroll
        for (int m = 0; m < 4; ++m)
            #pragma unroll
            for (int n = 0; n < 4; ++n)
                acc[m][n] = __builtin_amdgcn_mfma_f32_16x16x32_bf16(af[m], bfr[n], acc[m][n], 0, 0, 0);
        asm volatile("s_waitcnt lgkmcnt(0)" ::: "memory");       // my buf[cur] reads serviced
        __builtin_amdgcn_sched_barrier(0);
        __builtin_amdgcn_s_barrier();          // #2: buf[cur] reusable next iter
        __builtin_amdgcn_sched_barrier(0);
    }

    if (n0 < 2048) {
        #pragma unroll
        for (int m = 0; m < 4; ++m)
            #pragma unroll
            for (int n = 0; n < 4; ++n) {
                int col = n0 + wc * 64 + n * 16 + lq;
                int row0 = m0 + wr * 64 + m * 16 + g * 4;
                #pragma unroll
                for (int r = 0; r < 4; ++r)
                    qk_rm[(size_t)(row0 + r) * 2048 + col] = f2bf(acc[m][n][r]);
            }
    } else {
        short* T = smraw;   // [128][136]
        #pragma unroll
        for (int m = 0; m < 4; ++m)
            #pragma unroll
            for (int n = 0; n < 4; ++n) {
                int cl = wc * 64 + n * 16 + lq;
                int rl0 = wr * 64 + m * 16 + g * 4;
                union { short sh[4]; int2 w; } u;
                #pragma unroll
                for (int r = 0; r < 4; ++r) u.sh[r] = f2bf(acc[m][n][r]);
                *(int2*)(&T[cl * 136 + rl0]) = u.w;
            }
        __syncthreads();
        const int b = m0 >> 11, sbase = m0 & 2047;
        const int h0 = (n0 - 2048) >> 6;
        #pragma unroll
        for (int i = 0; i < 8; ++i) {
            int c2 = i * 256 + t;
            int rv = c2 >> 4;
            int sc = (c2 & 15) << 3;
            int h = h0 + (rv >> 6), dh = rv & 63;
            i128 v = *(const i128*)(&T[rv * 136 + sc]);
            *(i128*)(&vto[((size_t)((b * NH + h) * DH + dh)) * S_LEN + sbase + sc]) = v;
        }
    }
}

// ---------------- out GEMM: attno (M x 1024) @ wout_t (1024 x 1024) -> fp32, BK=64 ----------------
// counted-vmcnt two-barrier pipeline + T2 chunk-XOR swizzle (was a 16-way bank conflict)
__global__ __launch_bounds__(256, 2)
void gemm_out(const short* __restrict__ A, const short* __restrict__ Bt,
              float* __restrict__ co)
{
    __shared__ __align__(16) short Al[2][128 * 64];
    __shared__ __align__(16) short Bl[2][128 * 64];
    const int K = HDIM, N = HDIM;
    const int t = threadIdx.x;
    const int lane = t & 63;
    const int wave = t >> 6;
    const int wr = wave >> 1, wc = wave & 1;
    const int m0 = blockIdx.y * 128, n0 = blockIdx.x * 128;
    const int lq = lane & 15;
    const int g = lane >> 4;

    f32x4 acc[4][4];
    #pragma unroll
    for (int m = 0; m < 4; ++m)
        #pragma unroll
        for (int n = 0; n < 4; ++n)
            acc[m][n] = (f32x4){0.f, 0.f, 0.f, 0.f};

    // stage: chunk -> row=chunk>>3, position (chunk&7); global col chunk = pos ^ (row&7)
    const int ccol = (((t & 7) ^ ((t >> 3) & 7)) << 3);     // same for all q groups
    // read: logical chunk (ks*4+g) of row (..+lq) sits at position (ks*4+g) ^ (lq&7)
    const int pk[2] = { (((0 * 4 + g) ^ (lq & 7)) << 3), (((1 * 4 + g) ^ (lq & 7)) << 3) };

    auto stage = [&](int k0, int sb) {
        #pragma unroll
        for (int q = 0; q < 4; ++q) {
            int row = q * 32 + (t >> 3);
            size_t dst = (size_t)(q * 256 + wave * 64) * 8;
            gload_lds16(&A[(size_t)(m0 + row) * K + k0 + ccol], &Al[sb][0] + dst);
            gload_lds16(&Bt[(size_t)(n0 + row) * K + k0 + ccol], &Bl[sb][0] + dst);
        }
    };

    const int nk = K >> 6;   // 16
    stage(0, 0);             // 8 vmem outstanding
    for (int ki = 0; ki < nk; ++ki) {
        const int cur = ki & 1;
        if (ki + 1 < nk) {
            stage((ki + 1) << 6, cur ^ 1);
            asm volatile("s_waitcnt vmcnt(8)" ::: "memory");
        } else {
            asm volatile("s_waitcnt vmcnt(0)" ::: "memory");
        }
        __builtin_amdgcn_sched_barrier(0);
        __builtin_amdgcn_s_barrier();
        __builtin_amdgcn_sched_barrier(0);
        bfrag af[4][2], bfr[4][2];
        #pragma unroll
        for (int m = 0; m < 4; ++m)
            #pragma unroll
            for (int ks = 0; ks < 2; ++ks)
                af[m][ks] = *(const bfrag*)(&Al[cur][(wr * 64 + m * 16 + lq) * 64 + pk[ks]]);
        #pragma unroll
        for (int n = 0; n < 4; ++n)
            #pragma unroll
            for (int ks = 0; ks < 2; ++ks)
                bfr[n][ks] = *(const bfrag*)(&Bl[cur][(wc * 64 + n * 16 + lq) * 64 + pk[ks]]);
        #pragma unroll
        for (int m = 0; m < 4; ++m)
            #pragma unroll
            for (int n = 0; n < 4; ++n) {
                acc[m][n] = __builtin_amdgcn_mfma_f32_16x16x32_bf16(af[m][0], bfr[n][0], acc[m][n], 0, 0, 0);
                acc[m][n] = __builtin_amdgcn_mfma_f32_16x16x32_bf16(af[m][1], bfr[n][1], acc[m][n], 0, 0, 0);
            }
        asm volatile("s_waitcnt lgkmcnt(0)" ::: "memory");
        __builtin_amdgcn_sched_barrier(0);
        __builtin_amdgcn_s_barrier();
        __builtin_amdgcn_sched_barrier(0);
    }

    #pragma unroll
    for (int m = 0; m < 4; ++m)
        #pragma unroll
        for (int n = 0; n < 4; ++n) {
            int col = n0 + wc * 64 + n * 16 + lq;
            int row0 = m0 + wr * 64 + m * 16 + g * 4;
            #pragma unroll
            for (int r = 0; r < 4; ++r)
                co[(size_t)(row0 + r) * N + col] = acc[m][n][r];
        }
}

// ---------------- sliding-window flash attention: 64-q blocks, deferred-PV, counted vmcnt, defer-max ----------------
__global__ __launch_bounds__(256, 4)
void attn_kernel(const short* __restrict__ qk, const short* __restrict__ vt,
                 short* __restrict__ attno)
{
    __shared__ __align__(16) short Kl[2][64 * 64];
    __shared__ __align__(16) short Vl[2][64 * 64];
    __shared__ __align__(16) short Pl[4][16 * 64];

    const int bid = blockIdx.x;
    const int logical = (bid & 7) * 128 + (bid >> 3);   // XCD-grouping (1024 % 8 == 0, bijective)
    const int qblk = logical & 31;
    const int bh = logical >> 5;
    const int b = bh >> 4, h = bh & 15;

    const int t = threadIdx.x;
    const int wave = t >> 6, lane = t & 63;
    const int qb0 = qblk * 64;
    const int i0 = qb0 + wave * 16;
    const short* qbase = qk + (size_t)b * S_LEN * 2048 + h * 64;
    const short* kbase = qk + (size_t)b * S_LEN * 2048 + 1024 + h * 64;
    const short* vp = vt + (size_t)bh * DH * S_LEN;
    char* myP = (char*)&Pl[wave][0];

    const int lq = lane & 15;
    const int g = lane >> 4;
    const int swz = (lq & 7) << 4;
    const int l7 = lq & 7;
    const int qi = i0 + lq;

    bfrag qf[2];
    qf[0] = *(const bfrag*)(&qbase[(size_t)(i0 + lq) * 2048 + (g << 3)]);
    qf[1] = *(const bfrag*)(&qbase[(size_t)(i0 + lq) * 2048 + 32 + (g << 3)]);

    f32x4 oacc[4];
    #pragma unroll
    for (int d = 0; d < 4; ++d) oacc[d] = (f32x4){0.f, 0.f, 0.f, 0.f};
    float m2 = -1e30f, lrun = 0.f, scale_prev = 1.f;
    bool defer_prev = true;
    const float QSCALE = 0.125f * 1.44269504f;

    bfrag pf_prev[2];
    bfrag vf_prev[2][4];

    int j_lo = qb0 - (WINSZ - 1);
    if (j_lo < 0) j_lo = 0;
    j_lo &= ~63;
    const int nT = ((qb0 + 64) - j_lo) >> 6;

    auto stage = [&](int jrel, short* kbuf, short* vbuf) {
        #pragma unroll
        for (int qq = 0; qq < 2; ++qq) {
            int chunk = qq * 256 + wave * 64 + lane;
            int row = chunk >> 3;
            int cc = (chunk & 7) ^ (row & 7);
            short* kdst = kbuf + (size_t)(qq * 256 + wave * 64) * 8;
            short* vdst = vbuf + (size_t)(qq * 256 + wave * 64) * 8;
            gload_lds16(kbase + (size_t)(j_lo + jrel + row) * 2048 + cc * 8, kdst);
            gload_lds16(vp + (size_t)row * S_LEN + j_lo + jrel + cc * 8, vdst);
        }
    };

    stage(0, Kl[0], Vl[0]);   // 4 vmem outstanding

    for (int ti = 0; ti < nT; ++ti) {
        const int cur = ti & 1;
        const int j0 = j_lo + ti * 64;
        const bool more = (ti + 1 < nT);
        if (more) stage((ti + 1) * 64, Kl[cur ^ 1], Vl[cur ^ 1]);   // +4 -> 8 outstanding

        // ---- deferred PV(ti-1): pure-register MFMA fills the load wait ----
        if (ti > 0) {
            if (!defer_prev) {
                #pragma unroll
                for (int d = 0; d < 4; ++d) {
                    f32x4 o = oacc[d];
                    o[0] *= scale_prev; o[1] *= scale_prev; o[2] *= scale_prev; o[3] *= scale_prev;
                    oacc[d] = o;
                }
            }
            __builtin_amdgcn_s_setprio(1);
            #pragma unroll
            for (int kt = 0; kt < 2; ++kt)
                #pragma unroll
                for (int d = 0; d < 4; ++d)
                    oacc[d] = __builtin_amdgcn_mfma_f32_16x16x32_bf16(vf_prev[kt][d], pf_prev[kt], oacc[d], 0, 0, 0);
            __builtin_amdgcn_s_setprio(0);
        }

        if (more) asm volatile("s_waitcnt vmcnt(4)" ::: "memory");
        else      asm volatile("s_waitcnt vmcnt(0)" ::: "memory");
        __builtin_amdgcn_sched_barrier(0);
        __builtin_amdgcn_s_barrier();        // #1: all waves' tile-ti DMA visible
        __builtin_amdgcn_sched_barrier(0);

        const short* Kc = Kl[cur];
        const short* Vc = Vl[cur];

        // ---- QK^T swapped ----
        f32x4 sc[4];
        __builtin_amdgcn_s_setprio(1);
        #pragma unroll
        for (int tc = 0; tc < 4; ++tc) {
            bfrag a0 = *(const bfrag*)(&Kc[(tc * 16 + lq) * 64 + ((g ^ l7) << 3)]);
            bfrag a1 = *(const bfrag*)(&Kc[(tc * 16 + lq) * 64 + (((4 | g) ^ l7) << 3)]);
            f32x4 z = (f32x4){0.f, 0.f, 0.f, 0.f};
            z = __builtin_amdgcn_mfma_f32_16x16x32_bf16(a0, qf[0], z, 0, 0, 0);
            z = __builtin_amdgcn_mfma_f32_16x16x32_bf16(a1, qf[1], z, 0, 0, 0);
            sc[tc] = z;
        }
        __builtin_amdgcn_s_setprio(0);

        // ---- softmax (per-lane + 2 shuffles) with defer-max (T13, THR=8) ----
        const bool nomask = (j0 >= i0 - (WINSZ - 16)) && (j0 + 63 <= i0);
        float s[4][4];
        float pm = -1e30f;
        #pragma unroll
        for (int tc = 0; tc < 4; ++tc)
            #pragma unroll
            for (int r = 0; r < 4; ++r) {
                float sv = sc[tc][r] * QSCALE;
                if (!nomask) {
                    int kj = j0 + tc * 16 + 4 * g + r;
                    sv = ((kj <= qi) && (kj > qi - WINSZ)) ? sv : -1e30f;
                }
                s[tc][r] = sv;
                pm = fmaxf(pm, sv);
            }
        pm = fmaxf(pm, __shfl_xor(pm, 16));
        pm = fmaxf(pm, __shfl_xor(pm, 32));
        bool defer_i = __all(pm <= m2 + 8.f);
        float scale_i = 1.f;
        if (!defer_i) {
            float mnew = fmaxf(m2, pm);
            scale_i = exp2f(m2 - mnew);
            m2 = mnew;
        }
        float p[4][4];
        float rs = 0.f;
        #pragma unroll
        for (int tc = 0; tc < 4; ++tc)
            #pragma unroll
            for (int r = 0; r < 4; ++r) {
                p[tc][r] = exp2f(s[tc][r] - m2);
                rs += p[tc][r];
            }
        rs += __shfl_xor(rs, 16);
        rs += __shfl_xor(rs, 32);
        lrun = lrun * scale_i + rs;
        scale_prev = scale_i;
        defer_prev = defer_i;

        // ---- P(ti) -> LDS, then P/V reads for NEXT iter ----
        #pragma unroll
        for (int tc = 0; tc < 4; ++tc) {
            union { short sh[4]; int2 w; } u;
            u.sh[0] = f2bf(p[tc][0]); u.sh[1] = f2bf(p[tc][1]);
            u.sh[2] = f2bf(p[tc][2]); u.sh[3] = f2bf(p[tc][3]);
            int wb = (lq * 128 + tc * 32 + g * 8) ^ swz;
            *(int2*)(myP + wb) = u.w;
        }
        #pragma unroll
        for (int kt = 0; kt < 2; ++kt) {
            int rb = (lq * 128 + kt * 64 + g * 16) ^ swz;
            pf_prev[kt] = *(const bfrag*)(myP + rb);
            #pragma unroll
            for (int d = 0; d < 4; ++d)
                vf_prev[kt][d] = *(const bfrag*)(&Vc[(d * 16 + lq) * 64 + (((kt * 4 + g) ^ l7) << 3)]);
        }
        asm volatile("s_waitcnt lgkmcnt(0)" ::: "memory");
        __builtin_amdgcn_sched_barrier(0);
        __builtin_amdgcn_s_barrier();        // #2: buf[cur] reusable next iter
        __builtin_amdgcn_sched_barrier(0);
    }

    // ---- flush PV(nT-1) ----
    if (!defer_prev) {
        #pragma unroll
        for (int d = 0; d < 4; ++d) {
            f32x4 o = oacc[d];
            o[0] *= scale_prev; o[1] *= scale_prev; o[2] *= scale_prev; o[3] *= scale_prev;
            oacc[d] = o;
        }
    }
    #pragma unroll
    for (int kt = 0; kt < 2; ++kt)
        #pragma unroll
        for (int d = 0; d < 4; ++d)
            oacc[d] = __builtin_amdgcn_mfma_f32_16x16x32_bf16(vf_prev[kt][d], pf_prev[kt], oacc[d], 0, 0, 0);

    const float inv_l = 1.f / lrun;
    size_t rowbase = ((size_t)(b * S_LEN + qi)) * HDIM + h * DH;
    #pragma unroll
    for (int d = 0; d < 4; ++d) {
        union { short sh[4]; int2 w; } u;
        #pragma unroll
        for (int r = 0; r < 4; ++r)
            u.sh[r] = f2bf(oacc[d][r] * inv_l);
        *(int2*)(&attno[rowbase + d * 16 + 4 * g]) = u.w;
    }
}

extern "C" void kernel_launch(void* const* d_in, const int* in_sizes, int n_in,
                              void* d_out, int out_size, void* d_ws, size_t ws_size,
                              hipStream_t stream) {
    const float* x = (const float*)d_in[0];
    const float* Wqkv = (const float*)d_in[1];
    const float* Wout = (const float*)d_in[2];
    float* out = (float*)d_out;
    char* ws = (char*)d_ws;

    short* x_bf   = (short*)(ws);                    // 4096x1024 bf16 (8 MB); reused as attno
    short* wqkv_t = (short*)(ws + 8388608);          // 3072x1024      (6 MB)
    short* wout_t = (short*)(ws + 14680064);         // 1024x1024      (2 MB)
    short* qk_rm  = (short*)(ws + 16777216);         // 4096x2048 bf16 (16 MB)
    short* v_t    = (short*)(ws + 33554432);         // [b][h][dh][s]  (8 MB)
    short* attno  = x_bf;                            // alias: x_bf dead after QKV GEMM

    prep_kernel<<<8192, 256, 0, stream>>>(x, Wqkv, Wout, x_bf, wqkv_t, wout_t);
    gemm_qkv<<<dim3(24, 32), 256, 0, stream>>>(x_bf, wqkv_t, qk_rm, v_t);
    attn_kernel<<<dim3(BATCH * NH * (S_LEN / 64)), 256, 0, stream>>>(qk_rm, v_t, attno);
    gemm_out<<<dim3(8, 32), 256, 0, stream>>>(attno, wout_t, out);
}